// Round 4
// baseline (341.931 us; speedup 1.0000x reference)
//
#include <hip/hip_runtime.h>

typedef float f32x4  __attribute__((ext_vector_type(4)));
typedef _Float16 f16x8  __attribute__((ext_vector_type(8)));
typedef _Float16 f16x4v __attribute__((ext_vector_type(4)));
typedef _Float16 f16x8v __attribute__((ext_vector_type(8)));

__device__ inline void load_lds16(const _Float16* g, _Float16* l) {
    __builtin_amdgcn_global_load_lds((const __attribute__((address_space(1))) void*)g,
                                     (__attribute__((address_space(3))) void*)l, 16, 0, 0);
}

// ---------------------------------------------------------------------------
// convert_h: fp32 -> fp16 (hi only; A-side operands need no lo term)
// ---------------------------------------------------------------------------
__global__ __launch_bounds__(256)
void convert_h(const float* __restrict__ X, _Float16* __restrict__ H, long n4)
{
    long i = (long)blockIdx.x * 256 + threadIdx.x;
    if (i >= n4) return;
    f32x4 v = ((const f32x4*)X)[i];
    f16x4v h;
#pragma unroll
    for (int k = 0; k < 4; ++k) h[k] = (_Float16)v[k];
    ((f16x4v*)H)[i] = h;
}

// ---------------------------------------------------------------------------
// transpose_w3: Wq,Wk -> W2 [2048][2048] fp16 stacked-K (k<1024 hi, k>=1024 lo)
//               Wv -> Wvt [1024][1024] fp16 hi. One dispatch, z = 0/1/2.
// ---------------------------------------------------------------------------
__global__ __launch_bounds__(256)
void transpose_w3(const float* __restrict__ Wq, const float* __restrict__ Wk,
                  const float* __restrict__ Wv,
                  _Float16* __restrict__ W2, _Float16* __restrict__ Wvt, int D)
{
    const int z = blockIdx.z;
    const float* W = (z == 0) ? Wq : (z == 1) ? Wk : Wv;

    __shared__ float t[32][33];
    const int tid = threadIdx.x;
    const int bx = blockIdx.x * 32, by = blockIdx.y * 32;
    const int c = tid & 31, r0 = tid >> 5;
#pragma unroll
    for (int r = r0; r < 32; r += 8)
        t[r][c] = W[(long)(by + r) * D + bx + c];
    __syncthreads();
#pragma unroll
    for (int r = r0; r < 32; r += 8) {
        float v = t[c][r];                       // = W[by+c][bx+r]
        _Float16 h = (_Float16)v;
        if (z < 2) {
            const long nrow = (long)z * D + bx + r;      // stacked Q|K rows
            W2[nrow * 2 * D + by + c]     = h;           // hi at k
            W2[nrow * 2 * D + D + by + c] = (_Float16)(v - (float)h);  // lo at k+D
        } else {
            Wvt[(long)(bx + r) * D + by + c] = h;
        }
    }
}

// ---------------------------------------------------------------------------
// proj8 (v3): 256x256 projection GEMM, K-sliced ring-4 counted-vmcnt schedule.
// R3 change: staging unit = BK=32 K-slice (16 KB contiguous), ring of 4 slots
// per operand (8 x 16KB = 128 KB). Per K-step: 2 phases
//   even(s): read B(s) 4 frags + A(s) rows0-3; stage A(s+2); bar; 16 MFMA; bar
//   odd(s) : read A(s) rows4-7;               stage B(s+2); vmcnt(4); bar;
//            16 MFMA; bar
// The single vmcnt(4) per K-step guards slot s+1 while s+2's 4 loads remain
// in flight -> never drains to 0 in steady state (T3/T4, m218's +38-73% lever;
// R2's schedule drained every K-tile -> 30% MfmaUtil).
// Slice layout: [128 rp][8 granules], granule glog = (row>>7)*4 + kquad,
// phys granule = glog ^ (rp&7)  (3-bit XOR, 2-way max bank aliasing = free).
// Staging source pre-permuted by the same involution (rule 21).
// Waves 2M x 4N (wave tile 128x64), acc[8][4] f32x4 in AGPRs.
//   blocks 0..255 : QK, K'=2048 (A = x dup along K; B = W2 hi|lo stacked).
//   blocks 256..383: V, K=1024, transposed epilogue -> Vt [B][D][S].
// ---------------------------------------------------------------------------
__global__ __launch_bounds__(512)
void proj8(const _Float16* __restrict__ x_h, const _Float16* __restrict__ W2,
           const _Float16* __restrict__ Wvt,
           _Float16* __restrict__ Q_h, _Float16* __restrict__ K_h,
           _Float16* __restrict__ K_l, _Float16* __restrict__ Vt,
           const float* __restrict__ bq, const float* __restrict__ bk,
           const float* __restrict__ bv)
{
    constexpr int D = 1024, SEQ = 2048;
    __shared__ __align__(16) _Float16 lds[65536];   // 128 KB: A slots [0,32768), B slots [32768,65536)

    const int orig = blockIdx.x;
    const bool isV = orig >= 256;
    int ct, rt, ldb, NT2;
    const _Float16* Bb;
    if (!isV) {
        const int x = orig & 7, i = orig >> 3;       // XCD-chunked: rt block of 4, all ct
        rt = x * 4 + (i & 3);  ct = i >> 2;          // ct in [0,8)
        Bb = W2;  ldb = 2 * D; NT2 = 64;             // 64 K-steps of 32
    } else {
        const int o = orig - 256, x = o & 7, i = o >> 3;
        rt = x * 4 + (i & 3);  ct = i >> 2;          // ct in [0,4)
        Bb = Wvt; ldb = D;     NT2 = 32;
    }
    const int row0 = rt * 256, col0 = ct * 256;

    const int tid = threadIdx.x;
    const int wave = tid >> 6, lane = tid & 63, l16 = lane & 15, quad = lane >> 4;
    const int wmh = (wave >> 2) * 128;     // M-half this wave owns (rows)
    const int wn  = (wave & 3) * 64;       // 64-col window this wave owns
    const int ahalf = (wave >> 2) << 2;    // glog upper bits for A reads

    // stage one 16 KB K-slice (256 rows x 32 k): phys granule p_ = q*512+tid,
    // rp = p_>>3, glog = (p_&7) ^ (rp&7); logical row = rp + 128*(glog>>2),
    // k-offset = (glog&3)*8. Source pre-permuted so the read-side XOR inverts.
#define STAGES(gb, ld, base0, kbase, dst)                                       \
    {                                                                           \
        _Pragma("unroll")                                                       \
        for (int q_ = 0; q_ < 2; ++q_) {                                        \
            const int p_ = q_ * 512 + tid;                                      \
            const int rp_ = p_ >> 3;                                            \
            const int gl_ = (p_ & 7) ^ (rp_ & 7);                               \
            const int row_ = rp_ + ((gl_ >> 2) << 7);                           \
            load_lds16((gb) + (long)((base0) + row_) * (ld) + (kbase) +         \
                           ((gl_ & 3) << 3),                                    \
                       (dst) + p_ * 8);                                         \
        }                                                                       \
    }

    // prologue: slices s=0,1 for A and B; wait slot0 only (slot1 stays in flight)
    STAGES(x_h, D, row0, 0,  lds);
    STAGES(Bb, ldb, col0, 0, lds + 32768);
    STAGES(x_h, D, row0, 32, lds + 8192);
    STAGES(Bb, ldb, col0, 32, lds + 32768 + 8192);
    asm volatile("s_waitcnt vmcnt(4)" ::: "memory");
    __syncthreads();

    f32x4 acc[8][4] = {};

    for (int s = 0; s < NT2; ++s) {
        _Float16* Asl = lds + (s & 3) * 8192;
        _Float16* Bsl = lds + 32768 + (s & 3) * 8192;
        const bool pf = (s + 2 < NT2);
        const int kA2 = ((s + 2) * 32) & (D - 1);   // A dup along K' for QK
        const int kB2 = (s + 2) * 32;

        // ---- even phase: B frags + A rows 0-3
        f16x8 b[4], a0[4];
#pragma unroll
        for (int j = 0; j < 4; ++j) {
            const int nr = wn + j * 16 + l16;
            const int rpb = nr & 127;
            const int gpb = ((((nr >> 7) << 2) | quad) ^ (rpb & 7));
            b[j] = *(const f16x8*)&Bsl[rpb * 64 + gpb * 8];
        }
#pragma unroll
        for (int il = 0; il < 4; ++il) {
            const int rp = il * 16 + l16;
            const int gpa = ((ahalf | quad) ^ (rp & 7));
            a0[il] = *(const f16x8*)&Asl[rp * 64 + gpa * 8];
        }
        if (pf) STAGES(x_h, D, row0, kA2, lds + ((s + 2) & 3) * 8192);
        __builtin_amdgcn_s_barrier();
        asm volatile("s_waitcnt lgkmcnt(0)" ::: "memory");
        __builtin_amdgcn_sched_barrier(0);
        __builtin_amdgcn_s_setprio(1);
#pragma unroll
        for (int il = 0; il < 4; ++il)
#pragma unroll
            for (int j = 0; j < 4; ++j)
                acc[il][j] = __builtin_amdgcn_mfma_f32_16x16x32_f16(
                    a0[il], b[j], acc[il][j], 0, 0, 0);
        __builtin_amdgcn_s_setprio(0);
        __builtin_amdgcn_s_barrier();

        // ---- odd phase: A rows 4-7 (b[] reused from registers)
        f16x8 a1[4];
#pragma unroll
        for (int il = 0; il < 4; ++il) {
            const int rp = (il + 4) * 16 + l16;
            const int gpa = ((ahalf | quad) ^ (rp & 7));
            a1[il] = *(const f16x8*)&Asl[rp * 64 + gpa * 8];
        }
        if (pf) STAGES(Bb, ldb, col0, kB2, lds + 32768 + ((s + 2) & 3) * 8192);
        // counted wait: guard slot s+1 (A,B staged 2 phases ago); slot s+2's
        // 4 loads stay in flight. Drains only at the final two steps.
        if (pf)                asm volatile("s_waitcnt vmcnt(4)" ::: "memory");
        else if (s + 1 < NT2)  asm volatile("s_waitcnt vmcnt(0)" ::: "memory");
        __builtin_amdgcn_s_barrier();
        asm volatile("s_waitcnt lgkmcnt(0)" ::: "memory");
        __builtin_amdgcn_sched_barrier(0);
        __builtin_amdgcn_s_setprio(1);
#pragma unroll
        for (int il = 0; il < 4; ++il)
#pragma unroll
            for (int j = 0; j < 4; ++j)
                acc[4 + il][j] = __builtin_amdgcn_mfma_f32_16x16x32_f16(
                    a1[il], b[j], acc[4 + il][j], 0, 0, 0);
        __builtin_amdgcn_s_setprio(0);
        __builtin_amdgcn_s_barrier();
    }

    if (!isV) {
        // ---- Q / K epilogue (tile is entirely Q or entirely K)
        const bool isQ = ct < 4;
        const float* bias = isQ ? bq : bk;
#pragma unroll
        for (int j = 0; j < 4; ++j) {
            const int colg = col0 + wn + j * 16 + l16;
            const int cc = isQ ? colg : colg - D;
            const float bval = bias[cc];
#pragma unroll
            for (int i = 0; i < 8; ++i) {
                const int rb = row0 + wmh + i * 16 + quad * 4;
#pragma unroll
                for (int r = 0; r < 4; ++r) {
                    const float v = acc[i][j][r] + bval;
                    const _Float16 h = (_Float16)v;
                    if (isQ) {
                        Q_h[(long)(rb + r) * D + cc] = h;
                    } else {
                        K_h[(long)(rb + r) * D + cc] = h;
                        K_l[(long)(rb + r) * D + cc] = (_Float16)(v - (float)h);
                    }
                }
            }
        }
    } else {
        // ---- V epilogue: transpose via LDS (reuse all 128 KB), XOR-swizzled
        _Float16* sVt = lds;                 // [256 cols][512B of rows] fp16
#pragma unroll
        for (int j = 0; j < 4; ++j) {
            const int cl = wn + j * 16 + l16;
            const float bval = bv[col0 + cl];
#pragma unroll
            for (int i = 0; i < 8; ++i) {
                f16x4v pk;
#pragma unroll
                for (int r = 0; r < 4; ++r) pk[r] = (_Float16)(acc[i][j][r] + bval);
                const int rowb = wmh * 2 + i * 32 + quad * 8;   // byte in 512B row
                const int sb = cl * 512 + (rowb ^ ((cl & 31) << 4));
                *(f16x4v*)((char*)sVt + sb) = pk;
            }
        }
        __syncthreads();
        const int bb = row0 >> 11;           // tiles never cross batches
        const int s0 = row0 & (SEQ - 1);
        for (int idx = tid; idx < 8192; idx += 512) {
            const int cl = idx >> 5, r8 = idx & 31;
            const int sb = cl * 512 + ((r8 * 16) ^ ((cl & 31) << 4));
            f16x8v v = *(const f16x8v*)&((char*)sVt)[sb];
            *(f16x8v*)&Vt[((long)bb * D + col0 + cl) * SEQ + s0 + r8 * 8] = v;
        }
    }
#undef STAGES
}

// ---------------------------------------------------------------------------
// gemm2: C = A @ B^T_layout (fp32 out). A fp16 [M][K] (hi only),
// B fp16 [N][K] hi (+ lo if BLO: 2-term accumulate). TM=128 x TNB, TK=32.
// MODE 1: causal packed triangular grid (x = live-tile id, TNB=64);
// MODE 2: PV, grid (x=rows heavy-first, y=cols), K bounded at (rt+1)*TM.
// ---------------------------------------------------------------------------
constexpr int TM = 128, TK = 32;

template<bool BLO, int MODE, int TNB>
__global__ __launch_bounds__(256)
void gemm2(const _Float16* __restrict__ Ah, long sA, int lda,
           const _Float16* __restrict__ Bh, const _Float16* __restrict__ Bl,
           long sB, int ldb,
           float* __restrict__ Cf, long sC, int ldc, int K)
{
    static_assert(MODE != 1 || TNB == 64, "packed causal decode assumes TNB=64");
    constexpr int NFJ = TNB / 32;
    constexpr int BRNDS = TNB / 64;

    int rt, ct;
    if (MODE == 1) {
        const int t = blockIdx.x;
        rt = (int)((sqrtf(4.0f * t + 1.0f) - 1.0f) * 0.5f);
        while (rt * (rt + 1) > t) --rt;
        while ((rt + 1) * (rt + 2) <= t) ++rt;
        ct = t - rt * (rt + 1);
    } else {
        rt = (gridDim.x - 1) - blockIdx.x;   // heavy rows first
        ct = blockIdx.y;
    }
    const int bz = blockIdx.z;

    const _Float16* gAh = Ah + (long)bz * sA;
    const _Float16* gBh = Bh + (long)bz * sB;
    const _Float16* gBl = BLO ? Bl + (long)bz * sB : nullptr;

    const int row0 = rt * TM, col0 = ct * TNB;
    const int k_end = (MODE == 2) ? min(K, (rt + 1) * TM) : K;

    __shared__ _Float16 sAh[TM * TK];
    __shared__ _Float16 sBh[TNB * TK];
    __shared__ _Float16 sBl[BLO ? TNB * TK : 8];

    const int tid = threadIdx.x;
    const int lane = tid & 63, wave = tid >> 6;
    const int l16 = lane & 15, quad = lane >> 4;
    const int wm = (wave >> 1) * 64, wn = (wave & 1) * (TNB / 2);

    f32x4 acc[4][NFJ] = {};

    for (int k0 = 0; k0 < k_end; k0 += TK) {
#pragma unroll
        for (int rnd = 0; rnd < 2; ++rnd) {
            const int row = rnd * 64 + (tid >> 2);
            const long gA = (long)(row0 + row) * lda + k0 + (tid & 3) * 8;
            load_lds16(gAh + gA, sAh + rnd * 2048 + tid * 8);
        }
#pragma unroll
        for (int rnd = 0; rnd < BRNDS; ++rnd) {
            const int row = rnd * 64 + (tid >> 2);
            const long gB = (long)(col0 + row) * ldb + k0 + (tid & 3) * 8;
            const int lofs = rnd * 2048 + tid * 8;
            load_lds16(gBh + gB, sBh + lofs);
            if (BLO) load_lds16(gBl + gB, sBl + lofs);
        }
        __syncthreads();

        f16x8 a[4], b_h[NFJ];
#pragma unroll
        for (int i = 0; i < 4; ++i)
            a[i] = *(const f16x8*)&sAh[(wm + i * 16 + l16) * TK + (quad << 3)];
#pragma unroll
        for (int j = 0; j < NFJ; ++j)
            b_h[j] = *(const f16x8*)&sBh[(wn + j * 16 + l16) * TK + (quad << 3)];

        if (BLO) {
            f16x8 b_l[NFJ];
#pragma unroll
            for (int j = 0; j < NFJ; ++j)
                b_l[j] = *(const f16x8*)&sBl[(wn + j * 16 + l16) * TK + (quad << 3)];
#pragma unroll
            for (int i = 0; i < 4; ++i)
#pragma unroll
                for (int j = 0; j < NFJ; ++j) {
                    acc[i][j] = __builtin_amdgcn_mfma_f32_16x16x32_f16(a[i], b_h[j], acc[i][j], 0, 0, 0);
                    acc[i][j] = __builtin_amdgcn_mfma_f32_16x16x32_f16(a[i], b_l[j], acc[i][j], 0, 0, 0);
                }
        } else {
#pragma unroll
            for (int i = 0; i < 4; ++i)
#pragma unroll
                for (int j = 0; j < NFJ; ++j)
                    acc[i][j] = __builtin_amdgcn_mfma_f32_16x16x32_f16(a[i], b_h[j], acc[i][j], 0, 0, 0);
        }
        __syncthreads();
    }

    float* cf = Cf + (long)bz * sC;
#pragma unroll
    for (int j = 0; j < NFJ; ++j) {
        const int col = col0 + wn + j * 16 + l16;
#pragma unroll
        for (int i = 0; i < 4; ++i) {
            const int rb = row0 + wm + i * 16 + quad * 4;
#pragma unroll
            for (int r = 0; r < 4; ++r)
                cf[(long)(rb + r) * ldc + col] = acc[i][j][r];
        }
    }
}

// ---------------------------------------------------------------------------
// softmax: causal, fp32 Sc row -> fp16 P row; loads only live 32B chunks,
// writes exactly the columns the PV GEMM will read (ceil((r+1)/128)*128).
// ---------------------------------------------------------------------------
__global__ __launch_bounds__(256)
void softmax_kernel(const float* __restrict__ Sc, _Float16* __restrict__ P, int seq)
{
    const int r = blockIdx.x, b = blockIdx.y;
    const float* row = Sc + ((long)b * seq + r) * seq;
    _Float16* prow = P + ((long)b * seq + r) * seq;
    const int tid = threadIdx.x;
    const int cmax = ((r >> 7) + 1) << 7;
    const int c0 = tid * 8;

    float v[8];
    f32x4 v0, v1;
    if (c0 <= r) {                 // chunk has at least one live column
        const f32x4* rp = (const f32x4*)row;
        v0 = rp[tid * 2];
        v1 = rp[tid * 2 + 1];
    } else {
        v0 = (f32x4)(-3.0e38f);
        v1 = (f32x4)(-3.0e38f);
    }
    float lmax = -3.0e38f;
#pragma unroll
    for (int k = 0; k < 4; ++k) {
        v[k]     = (c0 + k     <= r) ? v0[k] : -3.0e38f;
        v[k + 4] = (c0 + k + 4 <= r) ? v1[k] : -3.0e38f;
    }
#pragma unroll
    for (int k = 0; k < 8; ++k) lmax = fmaxf(lmax, v[k]);

    __shared__ float red[256];
    red[tid] = lmax; __syncthreads();
    for (int s = 128; s > 0; s >>= 1) {
        if (tid < s) red[tid] = fmaxf(red[tid], red[tid + s]);
        __syncthreads();
    }
    const float m = red[0];
    __syncthreads();

    float lsum = 0.0f;
#pragma unroll
    for (int k = 0; k < 8; ++k) {
        float e = (v[k] > -1.0e38f) ? __expf(v[k] - m) : 0.0f;
        v[k] = e;
        lsum += e;
    }
    red[tid] = lsum; __syncthreads();
    for (int s = 128; s > 0; s >>= 1) {
        if (tid < s) red[tid] += red[tid + s];
        __syncthreads();
    }
    const float inv = 1.0f / red[0];

    if (c0 < cmax) {
        f16x8v o;
#pragma unroll
        for (int k = 0; k < 8; ++k) o[k] = (_Float16)(v[k] * inv);
        ((f16x8v*)prow)[tid] = o;
    }
}

// ---------------------------------------------------------------------------
extern "C" void kernel_launch(void* const* d_in, const int* in_sizes, int n_in,
                              void* d_out, int out_size, void* d_ws, size_t ws_size,
                              hipStream_t stream)
{
    constexpr int B = 4, S = 2048, D = 1024;
    constexpr long MB = 1024 * 1024;
    const float* x  = (const float*)d_in[0];
    const float* Wq = (const float*)d_in[1];
    const float* bq = (const float*)d_in[2];
    const float* Wk = (const float*)d_in[3];
    const float* bk = (const float*)d_in[4];
    const float* Wv = (const float*)d_in[5];
    const float* bv = (const float*)d_in[6];
    float* out = (float*)d_out;

    // workspace layout (160 MB; Sc overlaps dead x/W regions)
    char* ws = (char*)d_ws;
    _Float16* x_h   = (_Float16*)(ws + 0);         // 16 MB
    _Float16* W2    = (_Float16*)(ws + 16 * MB);   // 8 MB [2048][2048] hi|lo stacked-K
    _Float16* Wvt_h = (_Float16*)(ws + 24 * MB);   // 2 MB [1024][1024]
    float*    Sc    = (float*)(ws + 0);            // 64 MB, after x/W dead
    _Float16* Q_h   = (_Float16*)(ws + 64 * MB);   // 16 MB [M][1024]
    _Float16* K_h   = (_Float16*)(ws + 80 * MB);   // 16 MB
    _Float16* K_l   = (_Float16*)(ws + 96 * MB);   // 16 MB
    _Float16* Vt    = (_Float16*)(ws + 112 * MB);  // 16 MB [B][D][S]
    _Float16* P     = (_Float16*)(ws + 128 * MB);  // 32 MB [B][S][S]

    const int M = B * S;  // 8192
    dim3 blk(256);

    // 1) convert x -> fp16 hi (A-side needs no lo)
    convert_h<<<(M * D / 4 + 255) / 256, blk, 0, stream>>>(x, x_h, (long)M * D / 4);
    // 2) weight transposes: Wq|Wk hi/lo stacked along K into W2; Wv hi into Wvt
    transpose_w3<<<dim3(D / 32, D / 32, 3), blk, 0, stream>>>(
        Wq, Wk, Wv, W2, Wvt_h, D);

    // 3) ring-4 counted-vmcnt 256x256 projections: blocks 0-255 QK, 256-383 V
    proj8<<<dim3(384), dim3(512), 0, stream>>>(
        x_h, W2, Wvt_h, Q_h, K_h, K_l, Vt, bq, bk, bv);

    // 4) scores = Q_h @ (K_h + K_l)^T (2-term, packed triangular, TN=64) -> fp32
    const int ntiles = (S / TM) * (S / TM + 1);   // 272 live 128x64 tiles
    gemm2<true, 1, 64><<<dim3(ntiles, 1, B), blk, 0, stream>>>(
        Q_h, (long)S * D, D, K_h, K_l, (long)S * D, D,
        Sc, (long)S * S, S, D);

    // 5) causal softmax: fp32 Sc -> fp16 P
    softmax_kernel<<<dim3(S, B), blk, 0, stream>>>(Sc, P, S);

    // 6) out = P @ V (K-loop bounded at diagonal, heavy rows first, TN=64)
    gemm2<false, 2, 64><<<dim3(S / TM, D / 64, B), blk, 0, stream>>>(
        P, (long)S * S, S, Vt, nullptr, (long)D * S, S,
        out, (long)S * D, D, S);
}

// Round 5
// 334.696 us; speedup vs baseline: 1.0216x; 1.0216x over previous
//
#include <hip/hip_runtime.h>

typedef float f32x4  __attribute__((ext_vector_type(4)));
typedef _Float16 f16x8  __attribute__((ext_vector_type(8)));
typedef _Float16 f16x4v __attribute__((ext_vector_type(4)));
typedef _Float16 f16x8v __attribute__((ext_vector_type(8)));

__device__ inline void load_lds16(const _Float16* g, _Float16* l) {
    __builtin_amdgcn_global_load_lds((const __attribute__((address_space(1))) void*)g,
                                     (__attribute__((address_space(3))) void*)l, 16, 0, 0);
}

// ---------------------------------------------------------------------------
// convert_h: fp32 -> fp16 (hi only; A-side operands need no lo term)
// ---------------------------------------------------------------------------
__global__ __launch_bounds__(256)
void convert_h(const float* __restrict__ X, _Float16* __restrict__ H, long n4)
{
    long i = (long)blockIdx.x * 256 + threadIdx.x;
    if (i >= n4) return;
    f32x4 v = ((const f32x4*)X)[i];
    f16x4v h;
#pragma unroll
    for (int k = 0; k < 4; ++k) h[k] = (_Float16)v[k];
    ((f16x4v*)H)[i] = h;
}

// ---------------------------------------------------------------------------
// transpose_w3: Wq,Wk -> W2 [2048][2048] fp16 stacked-K (k<1024 hi, k>=1024 lo)
//               Wv -> Wvt [1024][1024] fp16 hi. One dispatch, z = 0/1/2.
// ---------------------------------------------------------------------------
__global__ __launch_bounds__(256)
void transpose_w3(const float* __restrict__ Wq, const float* __restrict__ Wk,
                  const float* __restrict__ Wv,
                  _Float16* __restrict__ W2, _Float16* __restrict__ Wvt, int D)
{
    const int z = blockIdx.z;
    const float* W = (z == 0) ? Wq : (z == 1) ? Wk : Wv;

    __shared__ float t[32][33];
    const int tid = threadIdx.x;
    const int bx = blockIdx.x * 32, by = blockIdx.y * 32;
    const int c = tid & 31, r0 = tid >> 5;
#pragma unroll
    for (int r = r0; r < 32; r += 8)
        t[r][c] = W[(long)(by + r) * D + bx + c];
    __syncthreads();
#pragma unroll
    for (int r = r0; r < 32; r += 8) {
        float v = t[c][r];                       // = W[by+c][bx+r]
        _Float16 h = (_Float16)v;
        if (z < 2) {
            const long nrow = (long)z * D + bx + r;      // stacked Q|K rows
            W2[nrow * 2 * D + by + c]     = h;           // hi at k
            W2[nrow * 2 * D + D + by + c] = (_Float16)(v - (float)h);  // lo at k+D
        } else {
            Wvt[(long)(bx + r) * D + by + c] = h;
        }
    }
}

// ---------------------------------------------------------------------------
// proj8 (v4): 256x256 projection GEMM, K-sliced ring-4, SINGLE barrier/K-step.
// R4 change: R3's model closed exactly (4 barriers + lgkmcnt(0) pins serialize
// LDS-read (362cy) + MFMA (155cy) -> 30.0% MfmaUtil, measured 29.9/29.7).
// Fix: one raw s_barrier per K-step; no lgkm pins (plain vector ds_reads ->
// compiler emits counted lgkmcnt, so MFMA overlaps late reads; waves skew
// within the step so MFMA overlaps other waves' LDS service).
// Safety: ring-4 gives full-step margins. Landing: stage(s+1) issued @s-1,
// vmcnt(4)@s (oldest 4 drain), barrier@s, read@s+1. Overwrite: read(s)
// lgkm-consumed before MFMA(s) issue < barrier@s < stage(s+2)@s+... (1-step
// margin). vmcnt asm "memory" clobber stops next-step reads hoisting.
// Per K-step: 12 ds_read_b128 + 4 global_load_lds + 32 MFMA + 1 barrier.
// Slice layout: [128 rp][8 granules], glog = (row>>7)*4 + kquad,
// phys granule = glog ^ (rp&7); staging source pre-permuted (rule 21).
// Waves 2M x 4N (wave tile 128x64), acc[8][4] f32x4 in AGPRs.
//   blocks 0..255 : QK, K'=2048 (A = x dup along K; B = W2 hi|lo stacked).
//   blocks 256..383: V, K=1024, transposed epilogue -> Vt [B][D][S].
// ---------------------------------------------------------------------------
__global__ __launch_bounds__(512)
void proj8(const _Float16* __restrict__ x_h, const _Float16* __restrict__ W2,
           const _Float16* __restrict__ Wvt,
           _Float16* __restrict__ Q_h, _Float16* __restrict__ K_h,
           _Float16* __restrict__ K_l, _Float16* __restrict__ Vt,
           const float* __restrict__ bq, const float* __restrict__ bk,
           const float* __restrict__ bv)
{
    constexpr int D = 1024, SEQ = 2048;
    __shared__ __align__(16) _Float16 lds[65536];   // 128 KB: A slots [0,32768), B slots [32768,65536)

    const int orig = blockIdx.x;
    const bool isV = orig >= 256;
    int ct, rt, ldb, NT2;
    const _Float16* Bb;
    if (!isV) {
        const int x = orig & 7, i = orig >> 3;       // XCD-chunked: rt block of 4, all ct
        rt = x * 4 + (i & 3);  ct = i >> 2;          // ct in [0,8)
        Bb = W2;  ldb = 2 * D; NT2 = 64;             // 64 K-steps of 32
    } else {
        const int o = orig - 256, x = o & 7, i = o >> 3;
        rt = x * 4 + (i & 3);  ct = i >> 2;          // ct in [0,4)
        Bb = Wvt; ldb = D;     NT2 = 32;
    }
    const int row0 = rt * 256, col0 = ct * 256;

    const int tid = threadIdx.x;
    const int wave = tid >> 6, lane = tid & 63, l16 = lane & 15, quad = lane >> 4;
    const int wmh = (wave >> 2) * 128;     // M-half this wave owns (rows)
    const int wn  = (wave & 3) * 64;       // 64-col window this wave owns
    const int ahalf = (wave >> 2) << 2;    // glog upper bits for A reads

    // stage one 16 KB K-slice (256 rows x 32 k): phys granule p_ = q*512+tid,
    // rp = p_>>3, glog = (p_&7) ^ (rp&7); logical row = rp + 128*(glog>>2),
    // k-offset = (glog&3)*8. Source pre-permuted so the read-side XOR inverts.
#define STAGES(gb, ld, base0, kbase, dst)                                       \
    {                                                                           \
        _Pragma("unroll")                                                       \
        for (int q_ = 0; q_ < 2; ++q_) {                                        \
            const int p_ = q_ * 512 + tid;                                      \
            const int rp_ = p_ >> 3;                                            \
            const int gl_ = (p_ & 7) ^ (rp_ & 7);                               \
            const int row_ = rp_ + ((gl_ >> 2) << 7);                           \
            load_lds16((gb) + (long)((base0) + row_) * (ld) + (kbase) +         \
                           ((gl_ & 3) << 3),                                    \
                       (dst) + p_ * 8);                                         \
        }                                                                       \
    }

    // prologue: slices s=0,1 for A and B; wait slot0 only (slot1 stays in
    // flight across the raw barrier — do NOT use __syncthreads, it drains vm)
    STAGES(x_h, D, row0, 0,  lds);
    STAGES(Bb, ldb, col0, 0, lds + 32768);
    STAGES(x_h, D, row0, 32, lds + 8192);
    STAGES(Bb, ldb, col0, 32, lds + 32768 + 8192);
    asm volatile("s_waitcnt vmcnt(4)" ::: "memory");
    __builtin_amdgcn_s_barrier();

    f32x4 acc[8][4] = {};

    for (int s = 0; s < NT2; ++s) {
        _Float16* Asl = lds + (s & 3) * 8192;
        _Float16* Bsl = lds + 32768 + (s & 3) * 8192;
        const bool pf = (s + 2 < NT2);
        const int kA2 = ((s + 2) * 32) & (D - 1);   // A dup along K' for QK
        const int kB2 = (s + 2) * 32;

        // reads: B 4 frags + A rows 0-3; stage A(s+2); MFMA rows 0-3
        f16x8 b[4], a0[4];
#pragma unroll
        for (int j = 0; j < 4; ++j) {
            const int nr = wn + j * 16 + l16;
            const int rpb = nr & 127;
            const int gpb = ((((nr >> 7) << 2) | quad) ^ (rpb & 7));
            b[j] = *(const f16x8*)&Bsl[rpb * 64 + gpb * 8];
        }
#pragma unroll
        for (int il = 0; il < 4; ++il) {
            const int rp = il * 16 + l16;
            const int gpa = ((ahalf | quad) ^ (rp & 7));
            a0[il] = *(const f16x8*)&Asl[rp * 64 + gpa * 8];
        }
        if (pf) STAGES(x_h, D, row0, kA2, lds + ((s + 2) & 3) * 8192);
        __builtin_amdgcn_s_setprio(1);
#pragma unroll
        for (int il = 0; il < 4; ++il)
#pragma unroll
            for (int j = 0; j < 4; ++j)
                acc[il][j] = __builtin_amdgcn_mfma_f32_16x16x32_f16(
                    a0[il], b[j], acc[il][j], 0, 0, 0);
        __builtin_amdgcn_s_setprio(0);

        // reads: A rows 4-7; stage B(s+2); MFMA rows 4-7 (b[] reused)
        f16x8 a1[4];
#pragma unroll
        for (int il = 0; il < 4; ++il) {
            const int rp = (il + 4) * 16 + l16;
            const int gpa = ((ahalf | quad) ^ (rp & 7));
            a1[il] = *(const f16x8*)&Asl[rp * 64 + gpa * 8];
        }
        if (pf) STAGES(Bb, ldb, col0, kB2, lds + 32768 + ((s + 2) & 3) * 8192);
        __builtin_amdgcn_s_setprio(1);
#pragma unroll
        for (int il = 0; il < 4; ++il)
#pragma unroll
            for (int j = 0; j < 4; ++j)
                acc[4 + il][j] = __builtin_amdgcn_mfma_f32_16x16x32_f16(
                    a1[il], b[j], acc[4 + il][j], 0, 0, 0);
        __builtin_amdgcn_s_setprio(0);

        // single wait + single barrier per K-step (counted in steady state)
        if (pf)                asm volatile("s_waitcnt vmcnt(4)" ::: "memory");
        else if (s + 2 == NT2) asm volatile("s_waitcnt vmcnt(0)" ::: "memory");
        __builtin_amdgcn_s_barrier();
    }

    if (!isV) {
        // ---- Q / K epilogue (tile is entirely Q or entirely K)
        const bool isQ = ct < 4;
        const float* bias = isQ ? bq : bk;
#pragma unroll
        for (int j = 0; j < 4; ++j) {
            const int colg = col0 + wn + j * 16 + l16;
            const int cc = isQ ? colg : colg - D;
            const float bval = bias[cc];
#pragma unroll
            for (int i = 0; i < 8; ++i) {
                const int rb = row0 + wmh + i * 16 + quad * 4;
#pragma unroll
                for (int r = 0; r < 4; ++r) {
                    const float v = acc[i][j][r] + bval;
                    const _Float16 h = (_Float16)v;
                    if (isQ) {
                        Q_h[(long)(rb + r) * D + cc] = h;
                    } else {
                        K_h[(long)(rb + r) * D + cc] = h;
                        K_l[(long)(rb + r) * D + cc] = (_Float16)(v - (float)h);
                    }
                }
            }
        }
    } else {
        // ---- V epilogue: transpose via LDS (reuse all 128 KB), XOR-swizzled
        _Float16* sVt = lds;                 // [256 cols][512B of rows] fp16
#pragma unroll
        for (int j = 0; j < 4; ++j) {
            const int cl = wn + j * 16 + l16;
            const float bval = bv[col0 + cl];
#pragma unroll
            for (int i = 0; i < 8; ++i) {
                f16x4v pk;
#pragma unroll
                for (int r = 0; r < 4; ++r) pk[r] = (_Float16)(acc[i][j][r] + bval);
                const int rowb = wmh * 2 + i * 32 + quad * 8;   // byte in 512B row
                const int sb = cl * 512 + (rowb ^ ((cl & 31) << 4));
                *(f16x4v*)((char*)sVt + sb) = pk;
            }
        }
        __syncthreads();
        const int bb = row0 >> 11;           // tiles never cross batches
        const int s0 = row0 & (SEQ - 1);
        for (int idx = tid; idx < 8192; idx += 512) {
            const int cl = idx >> 5, r8 = idx & 31;
            const int sb = cl * 512 + ((r8 * 16) ^ ((cl & 31) << 4));
            f16x8v v = *(const f16x8v*)&((char*)sVt)[sb];
            *(f16x8v*)&Vt[((long)bb * D + col0 + cl) * SEQ + s0 + r8 * 8] = v;
        }
    }
#undef STAGES
}

// ---------------------------------------------------------------------------
// gemm2: C = A @ B^T_layout (fp32 out). A fp16 [M][K] (hi only),
// B fp16 [N][K] hi (+ lo if BLO: 2-term accumulate). TM=128 x TNB, TK=32.
// MODE 1: causal packed triangular grid (x = live-tile id, TNB=64);
// MODE 2: PV, grid (x=rows heavy-first, y=cols), K bounded at (rt+1)*TM.
// ---------------------------------------------------------------------------
constexpr int TM = 128, TK = 32;

template<bool BLO, int MODE, int TNB>
__global__ __launch_bounds__(256)
void gemm2(const _Float16* __restrict__ Ah, long sA, int lda,
           const _Float16* __restrict__ Bh, const _Float16* __restrict__ Bl,
           long sB, int ldb,
           float* __restrict__ Cf, long sC, int ldc, int K)
{
    static_assert(MODE != 1 || TNB == 64, "packed causal decode assumes TNB=64");
    constexpr int NFJ = TNB / 32;
    constexpr int BRNDS = TNB / 64;

    int rt, ct;
    if (MODE == 1) {
        const int t = blockIdx.x;
        rt = (int)((sqrtf(4.0f * t + 1.0f) - 1.0f) * 0.5f);
        while (rt * (rt + 1) > t) --rt;
        while ((rt + 1) * (rt + 2) <= t) ++rt;
        ct = t - rt * (rt + 1);
    } else {
        rt = (gridDim.x - 1) - blockIdx.x;   // heavy rows first
        ct = blockIdx.y;
    }
    const int bz = blockIdx.z;

    const _Float16* gAh = Ah + (long)bz * sA;
    const _Float16* gBh = Bh + (long)bz * sB;
    const _Float16* gBl = BLO ? Bl + (long)bz * sB : nullptr;

    const int row0 = rt * TM, col0 = ct * TNB;
    const int k_end = (MODE == 2) ? min(K, (rt + 1) * TM) : K;

    __shared__ _Float16 sAh[TM * TK];
    __shared__ _Float16 sBh[TNB * TK];
    __shared__ _Float16 sBl[BLO ? TNB * TK : 8];

    const int tid = threadIdx.x;
    const int lane = tid & 63, wave = tid >> 6;
    const int l16 = lane & 15, quad = lane >> 4;
    const int wm = (wave >> 1) * 64, wn = (wave & 1) * (TNB / 2);

    f32x4 acc[4][NFJ] = {};

    for (int k0 = 0; k0 < k_end; k0 += TK) {
#pragma unroll
        for (int rnd = 0; rnd < 2; ++rnd) {
            const int row = rnd * 64 + (tid >> 2);
            const long gA = (long)(row0 + row) * lda + k0 + (tid & 3) * 8;
            load_lds16(gAh + gA, sAh + rnd * 2048 + tid * 8);
        }
#pragma unroll
        for (int rnd = 0; rnd < BRNDS; ++rnd) {
            const int row = rnd * 64 + (tid >> 2);
            const long gB = (long)(col0 + row) * ldb + k0 + (tid & 3) * 8;
            const int lofs = rnd * 2048 + tid * 8;
            load_lds16(gBh + gB, sBh + lofs);
            if (BLO) load_lds16(gBl + gB, sBl + lofs);
        }
        __syncthreads();

        f16x8 a[4], b_h[NFJ];
#pragma unroll
        for (int i = 0; i < 4; ++i)
            a[i] = *(const f16x8*)&sAh[(wm + i * 16 + l16) * TK + (quad << 3)];
#pragma unroll
        for (int j = 0; j < NFJ; ++j)
            b_h[j] = *(const f16x8*)&sBh[(wn + j * 16 + l16) * TK + (quad << 3)];

        if (BLO) {
            f16x8 b_l[NFJ];
#pragma unroll
            for (int j = 0; j < NFJ; ++j)
                b_l[j] = *(const f16x8*)&sBl[(wn + j * 16 + l16) * TK + (quad << 3)];
#pragma unroll
            for (int i = 0; i < 4; ++i)
#pragma unroll
                for (int j = 0; j < NFJ; ++j) {
                    acc[i][j] = __builtin_amdgcn_mfma_f32_16x16x32_f16(a[i], b_h[j], acc[i][j], 0, 0, 0);
                    acc[i][j] = __builtin_amdgcn_mfma_f32_16x16x32_f16(a[i], b_l[j], acc[i][j], 0, 0, 0);
                }
        } else {
#pragma unroll
            for (int i = 0; i < 4; ++i)
#pragma unroll
                for (int j = 0; j < NFJ; ++j)
                    acc[i][j] = __builtin_amdgcn_mfma_f32_16x16x32_f16(a[i], b_h[j], acc[i][j], 0, 0, 0);
        }
        __syncthreads();
    }

    float* cf = Cf + (long)bz * sC;
#pragma unroll
    for (int j = 0; j < NFJ; ++j) {
        const int col = col0 + wn + j * 16 + l16;
#pragma unroll
        for (int i = 0; i < 4; ++i) {
            const int rb = row0 + wm + i * 16 + quad * 4;
#pragma unroll
            for (int r = 0; r < 4; ++r)
                cf[(long)(rb + r) * ldc + col] = acc[i][j][r];
        }
    }
}

// ---------------------------------------------------------------------------
// softmax: causal, fp32 Sc row -> fp16 P row; loads only live 32B chunks,
// writes exactly the columns the PV GEMM will read (ceil((r+1)/128)*128).
// ---------------------------------------------------------------------------
__global__ __launch_bounds__(256)
void softmax_kernel(const float* __restrict__ Sc, _Float16* __restrict__ P, int seq)
{
    const int r = blockIdx.x, b = blockIdx.y;
    const float* row = Sc + ((long)b * seq + r) * seq;
    _Float16* prow = P + ((long)b * seq + r) * seq;
    const int tid = threadIdx.x;
    const int cmax = ((r >> 7) + 1) << 7;
    const int c0 = tid * 8;

    float v[8];
    f32x4 v0, v1;
    if (c0 <= r) {                 // chunk has at least one live column
        const f32x4* rp = (const f32x4*)row;
        v0 = rp[tid * 2];
        v1 = rp[tid * 2 + 1];
    } else {
        v0 = (f32x4)(-3.0e38f);
        v1 = (f32x4)(-3.0e38f);
    }
    float lmax = -3.0e38f;
#pragma unroll
    for (int k = 0; k < 4; ++k) {
        v[k]     = (c0 + k     <= r) ? v0[k] : -3.0e38f;
        v[k + 4] = (c0 + k + 4 <= r) ? v1[k] : -3.0e38f;
    }
#pragma unroll
    for (int k = 0; k < 8; ++k) lmax = fmaxf(lmax, v[k]);

    __shared__ float red[256];
    red[tid] = lmax; __syncthreads();
    for (int s = 128; s > 0; s >>= 1) {
        if (tid < s) red[tid] = fmaxf(red[tid], red[tid + s]);
        __syncthreads();
    }
    const float m = red[0];
    __syncthreads();

    float lsum = 0.0f;
#pragma unroll
    for (int k = 0; k < 8; ++k) {
        float e = (v[k] > -1.0e38f) ? __expf(v[k] - m) : 0.0f;
        v[k] = e;
        lsum += e;
    }
    red[tid] = lsum; __syncthreads();
    for (int s = 128; s > 0; s >>= 1) {
        if (tid < s) red[tid] += red[tid + s];
        __syncthreads();
    }
    const float inv = 1.0f / red[0];

    if (c0 < cmax) {
        f16x8v o;
#pragma unroll
        for (int k = 0; k < 8; ++k) o[k] = (_Float16)(v[k] * inv);
        ((f16x8v*)prow)[tid] = o;
    }
}

// ---------------------------------------------------------------------------
extern "C" void kernel_launch(void* const* d_in, const int* in_sizes, int n_in,
                              void* d_out, int out_size, void* d_ws, size_t ws_size,
                              hipStream_t stream)
{
    constexpr int B = 4, S = 2048, D = 1024;
    constexpr long MB = 1024 * 1024;
    const float* x  = (const float*)d_in[0];
    const float* Wq = (const float*)d_in[1];
    const float* bq = (const float*)d_in[2];
    const float* Wk = (const float*)d_in[3];
    const float* bk = (const float*)d_in[4];
    const float* Wv = (const float*)d_in[5];
    const float* bv = (const float*)d_in[6];
    float* out = (float*)d_out;

    // workspace layout (160 MB; Sc overlaps dead x/W regions)
    char* ws = (char*)d_ws;
    _Float16* x_h   = (_Float16*)(ws + 0);         // 16 MB
    _Float16* W2    = (_Float16*)(ws + 16 * MB);   // 8 MB [2048][2048] hi|lo stacked-K
    _Float16* Wvt_h = (_Float16*)(ws + 24 * MB);   // 2 MB [1024][1024]
    float*    Sc    = (float*)(ws + 0);            // 64 MB, after x/W dead
    _Float16* Q_h   = (_Float16*)(ws + 64 * MB);   // 16 MB [M][1024]
    _Float16* K_h   = (_Float16*)(ws + 80 * MB);   // 16 MB
    _Float16* K_l   = (_Float16*)(ws + 96 * MB);   // 16 MB
    _Float16* Vt    = (_Float16*)(ws + 112 * MB);  // 16 MB [B][D][S]
    _Float16* P     = (_Float16*)(ws + 128 * MB);  // 32 MB [B][S][S]

    const int M = B * S;  // 8192
    dim3 blk(256);

    // 1) convert x -> fp16 hi (A-side needs no lo)
    convert_h<<<(M * D / 4 + 255) / 256, blk, 0, stream>>>(x, x_h, (long)M * D / 4);
    // 2) weight transposes: Wq|Wk hi/lo stacked along K into W2; Wv hi into Wvt
    transpose_w3<<<dim3(D / 32, D / 32, 3), blk, 0, stream>>>(
        Wq, Wk, Wv, W2, Wvt_h, D);

    // 3) single-barrier ring-4 256x256 projections: blocks 0-255 QK, 256-383 V
    proj8<<<dim3(384), dim3(512), 0, stream>>>(
        x_h, W2, Wvt_h, Q_h, K_h, K_l, Vt, bq, bk, bv);

    // 4) scores = Q_h @ (K_h + K_l)^T (2-term, packed triangular, TN=64) -> fp32
    const int ntiles = (S / TM) * (S / TM + 1);   // 272 live 128x64 tiles
    gemm2<true, 1, 64><<<dim3(ntiles, 1, B), blk, 0, stream>>>(
        Q_h, (long)S * D, D, K_h, K_l, (long)S * D, D,
        Sc, (long)S * S, S, D);

    // 5) causal softmax: fp32 Sc -> fp16 P
    softmax_kernel<<<dim3(S, B), blk, 0, stream>>>(Sc, P, S);

    // 6) out = P @ V (K-loop bounded at diagonal, heavy rows first, TN=64)
    gemm2<false, 2, 64><<<dim3(S / TM, D / 64, B), blk, 0, stream>>>(
        P, (long)S * S, S, Vt, nullptr, (long)D * S, S,
        out, (long)S * D, D, S);
}

// Round 6
// 317.648 us; speedup vs baseline: 1.0764x; 1.0537x over previous
//
#include <hip/hip_runtime.h>

typedef float f32x4  __attribute__((ext_vector_type(4)));
typedef _Float16 f16x8  __attribute__((ext_vector_type(8)));
typedef _Float16 f16x4v __attribute__((ext_vector_type(4)));
typedef _Float16 f16x8v __attribute__((ext_vector_type(8)));

__device__ inline void load_lds16(const _Float16* g, _Float16* l) {
    __builtin_amdgcn_global_load_lds((const __attribute__((address_space(1))) void*)g,
                                     (__attribute__((address_space(3))) void*)l, 16, 0, 0);
}

// ---------------------------------------------------------------------------
// convert_h: fp32 -> fp16 (hi only; A-side operands need no lo term)
// ---------------------------------------------------------------------------
__global__ __launch_bounds__(256)
void convert_h(const float* __restrict__ X, _Float16* __restrict__ H, long n4)
{
    long i = (long)blockIdx.x * 256 + threadIdx.x;
    if (i >= n4) return;
    f32x4 v = ((const f32x4*)X)[i];
    f16x4v h;
#pragma unroll
    for (int k = 0; k < 4; ++k) h[k] = (_Float16)v[k];
    ((f16x4v*)H)[i] = h;
}

// ---------------------------------------------------------------------------
// transpose_w3: Wq,Wk -> W2 [2048][2048] fp16 stacked-K (k<1024 hi, k>=1024 lo)
//               Wv -> Wvt [1024][1024] fp16 hi. One dispatch, z = 0/1/2.
// ---------------------------------------------------------------------------
__global__ __launch_bounds__(256)
void transpose_w3(const float* __restrict__ Wq, const float* __restrict__ Wk,
                  const float* __restrict__ Wv,
                  _Float16* __restrict__ W2, _Float16* __restrict__ Wvt, int D)
{
    const int z = blockIdx.z;
    const float* W = (z == 0) ? Wq : (z == 1) ? Wk : Wv;

    __shared__ float t[32][33];
    const int tid = threadIdx.x;
    const int bx = blockIdx.x * 32, by = blockIdx.y * 32;
    const int c = tid & 31, r0 = tid >> 5;
#pragma unroll
    for (int r = r0; r < 32; r += 8)
        t[r][c] = W[(long)(by + r) * D + bx + c];
    __syncthreads();
#pragma unroll
    for (int r = r0; r < 32; r += 8) {
        float v = t[c][r];                       // = W[by+c][bx+r]
        _Float16 h = (_Float16)v;
        if (z < 2) {
            const long nrow = (long)z * D + bx + r;      // stacked Q|K rows
            W2[nrow * 2 * D + by + c]     = h;           // hi at k
            W2[nrow * 2 * D + D + by + c] = (_Float16)(v - (float)h);  // lo at k+D
        } else {
            Wvt[(long)(bx + r) * D + by + c] = h;
        }
    }
}

// Shared staging macro: one 16 KB K-slice (256 rows x 32 k) with NTHR threads.
// phys granule p_ = q*NTHR+tid, rp_ = p_>>3, glog = (p_&7)^(rp_&7);
// logical row = rp_ + 128*(glog>>2), k-off = (glog&3)*8. Source pre-permuted
// so the read-side XOR inverts (rule 21).
#define STAGES_T(NTHR, NQ, gb, ld, base0, kbase, dst)                           \
    {                                                                           \
        _Pragma("unroll")                                                       \
        for (int q_ = 0; q_ < (NQ); ++q_) {                                     \
            const int p_ = q_ * (NTHR) + tid;                                   \
            const int rp_ = p_ >> 3;                                            \
            const int gl_ = (p_ & 7) ^ (rp_ & 7);                               \
            const int row_ = rp_ + ((gl_ >> 2) << 7);                           \
            load_lds16((gb) + (long)((base0) + row_) * (ld) + (kbase) +         \
                           ((gl_ & 3) << 3),                                    \
                       (dst) + p_ * 8);                                         \
        }                                                                       \
    }

// ---------------------------------------------------------------------------
// proj8 (v4): 256x256 projection GEMM, K-sliced ring-4, single barrier/step.
// Per-step cost law (R4 post-mortem): time = 30 cyc x ds_read_b128 count/CU;
// 2M x 4N wave tiles = 96 reads/CU-step. Schedule variants are all null.
//   blocks 0..255 : QK, K'=2048 (A = x dup along K; B = W2 hi|lo stacked);
//                   ct<4 -> Q epilogue, else K -> Khl [M][2048] hi|lo cols.
//   blocks 256..383: V, K=1024, transposed epilogue -> Vt [B][D][S].
// ---------------------------------------------------------------------------
__global__ __launch_bounds__(512)
void proj8(const _Float16* __restrict__ x_h, const _Float16* __restrict__ W2,
           const _Float16* __restrict__ Wvt,
           _Float16* __restrict__ Q_h, _Float16* __restrict__ Khl,
           _Float16* __restrict__ Vt,
           const float* __restrict__ bq, const float* __restrict__ bk,
           const float* __restrict__ bv)
{
    constexpr int D = 1024, SEQ = 2048;
    __shared__ __align__(16) _Float16 lds[65536];   // 128 KB

    const int orig = blockIdx.x;
    const bool isV = orig >= 256;
    int ct, rt, ldb, NT2;
    const _Float16* Bb;
    if (!isV) {
        const int x = orig & 7, i = orig >> 3;
        rt = x * 4 + (i & 3);  ct = i >> 2;
        Bb = W2;  ldb = 2 * D; NT2 = 64;
    } else {
        const int o = orig - 256, x = o & 7, i = o >> 3;
        rt = x * 4 + (i & 3);  ct = i >> 2;
        Bb = Wvt; ldb = D;     NT2 = 32;
    }
    const int row0 = rt * 256, col0 = ct * 256;

    const int tid = threadIdx.x;
    const int wave = tid >> 6, lane = tid & 63, l16 = lane & 15, quad = lane >> 4;
    const int wmh = (wave >> 2) * 128;
    const int wn  = (wave & 3) * 64;
    const int ahalf = (wave >> 2) << 2;

    STAGES_T(512, 2, x_h, D, row0, 0,  lds);
    STAGES_T(512, 2, Bb, ldb, col0, 0, lds + 32768);
    STAGES_T(512, 2, x_h, D, row0, 32, lds + 8192);
    STAGES_T(512, 2, Bb, ldb, col0, 32, lds + 32768 + 8192);
    asm volatile("s_waitcnt vmcnt(4)" ::: "memory");
    __builtin_amdgcn_s_barrier();

    f32x4 acc[8][4] = {};

    for (int s = 0; s < NT2; ++s) {
        _Float16* Asl = lds + (s & 3) * 8192;
        _Float16* Bsl = lds + 32768 + (s & 3) * 8192;
        const bool pf = (s + 2 < NT2);
        const int kA2 = ((s + 2) * 32) & (D - 1);
        const int kB2 = (s + 2) * 32;

        f16x8 b[4], a0[4];
#pragma unroll
        for (int j = 0; j < 4; ++j) {
            const int nr = wn + j * 16 + l16;
            const int rpb = nr & 127;
            const int gpb = ((((nr >> 7) << 2) | quad) ^ (rpb & 7));
            b[j] = *(const f16x8*)&Bsl[rpb * 64 + gpb * 8];
        }
#pragma unroll
        for (int il = 0; il < 4; ++il) {
            const int rp = il * 16 + l16;
            const int gpa = ((ahalf | quad) ^ (rp & 7));
            a0[il] = *(const f16x8*)&Asl[rp * 64 + gpa * 8];
        }
        if (pf) STAGES_T(512, 2, x_h, D, row0, kA2, lds + ((s + 2) & 3) * 8192);
        __builtin_amdgcn_s_setprio(1);
#pragma unroll
        for (int il = 0; il < 4; ++il)
#pragma unroll
            for (int j = 0; j < 4; ++j)
                acc[il][j] = __builtin_amdgcn_mfma_f32_16x16x32_f16(
                    a0[il], b[j], acc[il][j], 0, 0, 0);
        __builtin_amdgcn_s_setprio(0);

        f16x8 a1[4];
#pragma unroll
        for (int il = 0; il < 4; ++il) {
            const int rp = (il + 4) * 16 + l16;
            const int gpa = ((ahalf | quad) ^ (rp & 7));
            a1[il] = *(const f16x8*)&Asl[rp * 64 + gpa * 8];
        }
        if (pf) STAGES_T(512, 2, Bb, ldb, col0, kB2, lds + 32768 + ((s + 2) & 3) * 8192);
        __builtin_amdgcn_s_setprio(1);
#pragma unroll
        for (int il = 0; il < 4; ++il)
#pragma unroll
            for (int j = 0; j < 4; ++j)
                acc[4 + il][j] = __builtin_amdgcn_mfma_f32_16x16x32_f16(
                    a1[il], b[j], acc[4 + il][j], 0, 0, 0);
        __builtin_amdgcn_s_setprio(0);

        if (pf)                asm volatile("s_waitcnt vmcnt(4)" ::: "memory");
        else if (s + 2 == NT2) asm volatile("s_waitcnt vmcnt(0)" ::: "memory");
        __builtin_amdgcn_s_barrier();
    }

    if (!isV) {
        const bool isQ = ct < 4;
        const float* bias = isQ ? bq : bk;
#pragma unroll
        for (int j = 0; j < 4; ++j) {
            const int colg = col0 + wn + j * 16 + l16;
            const int cc = isQ ? colg : colg - D;
            const float bval = bias[cc];
#pragma unroll
            for (int i = 0; i < 8; ++i) {
                const int rb = row0 + wmh + i * 16 + quad * 4;
#pragma unroll
                for (int r = 0; r < 4; ++r) {
                    const float v = acc[i][j][r] + bval;
                    const _Float16 h = (_Float16)v;
                    if (isQ) {
                        Q_h[(long)(rb + r) * D + cc] = h;
                    } else {
                        Khl[(long)(rb + r) * 2048 + cc] = h;
                        Khl[(long)(rb + r) * 2048 + 1024 + cc] = (_Float16)(v - (float)h);
                    }
                }
            }
        }
    } else {
        _Float16* sVt = lds;                 // [256 cols][512B of rows] fp16
#pragma unroll
        for (int j = 0; j < 4; ++j) {
            const int cl = wn + j * 16 + l16;
            const float bval = bv[col0 + cl];
#pragma unroll
            for (int i = 0; i < 8; ++i) {
                f16x4v pk;
#pragma unroll
                for (int r = 0; r < 4; ++r) pk[r] = (_Float16)(acc[i][j][r] + bval);
                const int rowb = wmh * 2 + i * 32 + quad * 8;
                const int sb = cl * 512 + (rowb ^ ((cl & 31) << 4));
                *(f16x4v*)((char*)sVt + sb) = pk;
            }
        }
        __syncthreads();
        const int bb = row0 >> 11;
        const int s0 = row0 & (SEQ - 1);
        for (int idx = tid; idx < 8192; idx += 512) {
            const int cl = idx >> 5, r8 = idx & 31;
            const int sb = cl * 512 + ((r8 * 16) ^ ((cl & 31) << 4));
            f16x8v v = *(const f16x8v*)&((char*)sVt)[sb];
            *(f16x8v*)&Vt[((long)bb * D + col0 + cl) * SEQ + s0 + r8 * 8] = v;
        }
    }
}

// ---------------------------------------------------------------------------
// gemm_sc: scores = Q @ (Khl)^T, 2-term via stacked K' = 2048 (A = Q dup-K).
// Exact clone of proj8's QK loop. 256x256 tiles, causal-packed triangular
// grid: 36 live tiles/batch (ct <= rt), all 64 slices -> perfectly balanced.
// Diagonal tiles compute above-diag garbage; softmax masks it.
// ---------------------------------------------------------------------------
__global__ __launch_bounds__(512)
void gemm_sc(const _Float16* __restrict__ Q, const _Float16* __restrict__ Khl,
             float* __restrict__ Sc)
{
    constexpr int D = 1024, S = 2048;
    __shared__ __align__(16) _Float16 lds[65536];   // 128 KB

    const int bz = blockIdx.y;
    const int t = blockIdx.x;
    int rt = (int)((sqrtf(8.0f * t + 1.0f) - 1.0f) * 0.5f);
    while (rt * (rt + 1) / 2 > t) --rt;
    while ((rt + 1) * (rt + 2) / 2 <= t) ++rt;
    const int ct = t - rt * (rt + 1) / 2;

    const _Float16* gA = Q + (long)bz * S * D;
    const _Float16* gB = Khl + (long)bz * S * 2048;
    const int row0 = rt * 256, col0 = ct * 256;
    constexpr int NT2 = 64;

    const int tid = threadIdx.x;
    const int wave = tid >> 6, lane = tid & 63, l16 = lane & 15, quad = lane >> 4;
    const int wmh = (wave >> 2) * 128;
    const int wn  = (wave & 3) * 64;
    const int ahalf = (wave >> 2) << 2;

    STAGES_T(512, 2, gA, D, row0, 0,  lds);
    STAGES_T(512, 2, gB, 2048, col0, 0, lds + 32768);
    STAGES_T(512, 2, gA, D, row0, 32, lds + 8192);
    STAGES_T(512, 2, gB, 2048, col0, 32, lds + 32768 + 8192);
    asm volatile("s_waitcnt vmcnt(4)" ::: "memory");
    __builtin_amdgcn_s_barrier();

    f32x4 acc[8][4] = {};

    for (int s = 0; s < NT2; ++s) {
        _Float16* Asl = lds + (s & 3) * 8192;
        _Float16* Bsl = lds + 32768 + (s & 3) * 8192;
        const bool pf = (s + 2 < NT2);
        const int kA2 = ((s + 2) * 32) & (D - 1);
        const int kB2 = (s + 2) * 32;

        f16x8 b[4], a0[4];
#pragma unroll
        for (int j = 0; j < 4; ++j) {
            const int nr = wn + j * 16 + l16;
            const int rpb = nr & 127;
            const int gpb = ((((nr >> 7) << 2) | quad) ^ (rpb & 7));
            b[j] = *(const f16x8*)&Bsl[rpb * 64 + gpb * 8];
        }
#pragma unroll
        for (int il = 0; il < 4; ++il) {
            const int rp = il * 16 + l16;
            const int gpa = ((ahalf | quad) ^ (rp & 7));
            a0[il] = *(const f16x8*)&Asl[rp * 64 + gpa * 8];
        }
        if (pf) STAGES_T(512, 2, gA, D, row0, kA2, lds + ((s + 2) & 3) * 8192);
        __builtin_amdgcn_s_setprio(1);
#pragma unroll
        for (int il = 0; il < 4; ++il)
#pragma unroll
            for (int j = 0; j < 4; ++j)
                acc[il][j] = __builtin_amdgcn_mfma_f32_16x16x32_f16(
                    a0[il], b[j], acc[il][j], 0, 0, 0);
        __builtin_amdgcn_s_setprio(0);

        f16x8 a1[4];
#pragma unroll
        for (int il = 0; il < 4; ++il) {
            const int rp = (il + 4) * 16 + l16;
            const int gpa = ((ahalf | quad) ^ (rp & 7));
            a1[il] = *(const f16x8*)&Asl[rp * 64 + gpa * 8];
        }
        if (pf) STAGES_T(512, 2, gB, 2048, col0, kB2, lds + 32768 + ((s + 2) & 3) * 8192);
        __builtin_amdgcn_s_setprio(1);
#pragma unroll
        for (int il = 0; il < 4; ++il)
#pragma unroll
            for (int j = 0; j < 4; ++j)
                acc[4 + il][j] = __builtin_amdgcn_mfma_f32_16x16x32_f16(
                    a1[il], b[j], acc[4 + il][j], 0, 0, 0);
        __builtin_amdgcn_s_setprio(0);

        if (pf)                asm volatile("s_waitcnt vmcnt(4)" ::: "memory");
        else if (s + 2 == NT2) asm volatile("s_waitcnt vmcnt(0)" ::: "memory");
        __builtin_amdgcn_s_barrier();
    }

    float* cf = Sc + (long)bz * S * S;
#pragma unroll
    for (int j = 0; j < 4; ++j) {
        const int col = col0 + wn + j * 16 + l16;
#pragma unroll
        for (int i = 0; i < 8; ++i) {
            const int rb = row0 + wmh + i * 16 + quad * 4;
#pragma unroll
            for (int r = 0; r < 4; ++r)
                cf[(long)(rb + r) * S + col] = acc[i][j][r];
        }
    }
}

// ---------------------------------------------------------------------------
// gemm_pv: out = P @ Vt^T-layout. 256x128 tiles, 256 threads / 4 waves
// (2M x 2N, wave tile 128x64), ring-4 BK=32, K bounded at (rt+1)*256
// (= softmax cmax). Heavy rows dispatched first. 96 KB LDS.
// Also probes 1-wave/SIMD viability for the read-count law.
// ---------------------------------------------------------------------------
__global__ __launch_bounds__(256)
void gemm_pv(const _Float16* __restrict__ P, const _Float16* __restrict__ Vt,
             float* __restrict__ Out)
{
    constexpr int D = 1024, S = 2048;
    __shared__ __align__(16) _Float16 lds[49152];   // 96 KB: A 4x8192, B 4x4096

    const int rt = 7 - (int)blockIdx.x;   // heavy rows first
    const int ct = blockIdx.y;            // 0..7, 128 cols each
    const int bz = blockIdx.z;
    const _Float16* gA = P + (long)bz * S * S;
    const _Float16* gB = Vt + (long)bz * D * S;
    const int row0 = rt * 256, col0 = ct * 128;
    const int NT2 = (rt + 1) * 8;

    const int tid = threadIdx.x;
    const int wave = tid >> 6, lane = tid & 63, l16 = lane & 15, quad = lane >> 4;
    const int wmh = (wave >> 1) * 128;
    const int wn  = (wave & 1) * 64;
    const int ahalf = (wave >> 1) << 2;

    // B slice: 128 rows x 32 k = 8 KB, fold 64: row = rp + 64*(gl>>2)
#define STAGEB_PV(kbase, dst)                                                   \
    {                                                                           \
        _Pragma("unroll")                                                       \
        for (int q_ = 0; q_ < 2; ++q_) {                                        \
            const int p_ = q_ * 256 + tid;                                      \
            const int rp_ = p_ >> 3;                                            \
            const int gl_ = (p_ & 7) ^ (rp_ & 7);                               \
            const int row_ = rp_ + ((gl_ >> 2) << 6);                           \
            load_lds16(gB + (long)(col0 + row_) * S + (kbase) +                 \
                           ((gl_ & 3) << 3),                                    \
                       (dst) + p_ * 8);                                         \
        }                                                                       \
    }

    STAGES_T(256, 4, gA, S, row0, 0,  lds);
    STAGEB_PV(0, lds + 32768);
    STAGES_T(256, 4, gA, S, row0, 32, lds + 8192);
    STAGEB_PV(32, lds + 32768 + 4096);
    asm volatile("s_waitcnt vmcnt(6)" ::: "memory");
    __builtin_amdgcn_s_barrier();

    f32x4 acc[8][4] = {};

    for (int s = 0; s < NT2; ++s) {
        _Float16* Asl = lds + (s & 3) * 8192;
        _Float16* Bsl = lds + 32768 + (s & 3) * 4096;
        const bool pf = (s + 2 < NT2);
        const int k2 = (s + 2) * 32;

        f16x8 b[4], a[8];
#pragma unroll
        for (int j = 0; j < 4; ++j) {
            const int nr = wn + j * 16 + l16;
            const int rpb = nr & 63;
            const int gpb = ((((nr >> 6) << 2) | quad) ^ (rpb & 7));
            b[j] = *(const f16x8*)&Bsl[rpb * 64 + gpb * 8];
        }
#pragma unroll
        for (int il = 0; il < 8; ++il) {
            const int rp = il * 16 + l16;
            const int gpa = ((ahalf | quad) ^ (rp & 7));
            a[il] = *(const f16x8*)&Asl[rp * 64 + gpa * 8];
        }
        if (pf) {
            STAGES_T(256, 4, gA, S, row0, k2, lds + ((s + 2) & 3) * 8192);
            STAGEB_PV(k2, lds + 32768 + ((s + 2) & 3) * 4096);
        }
        __builtin_amdgcn_s_setprio(1);
#pragma unroll
        for (int il = 0; il < 8; ++il)
#pragma unroll
            for (int j = 0; j < 4; ++j)
                acc[il][j] = __builtin_amdgcn_mfma_f32_16x16x32_f16(
                    a[il], b[j], acc[il][j], 0, 0, 0);
        __builtin_amdgcn_s_setprio(0);

        if (pf)                asm volatile("s_waitcnt vmcnt(6)" ::: "memory");
        else if (s + 2 == NT2) asm volatile("s_waitcnt vmcnt(0)" ::: "memory");
        __builtin_amdgcn_s_barrier();
    }

    float* cf = Out + (long)bz * S * D;
#pragma unroll
    for (int j = 0; j < 4; ++j) {
        const int col = col0 + wn + j * 16 + l16;
#pragma unroll
        for (int i = 0; i < 8; ++i) {
            const int rb = row0 + wmh + i * 16 + quad * 4;
#pragma unroll
            for (int r = 0; r < 4; ++r)
                cf[(long)(rb + r) * D + col] = acc[i][j][r];
        }
    }
#undef STAGEB_PV
}

// ---------------------------------------------------------------------------
// softmax: causal, fp32 Sc row -> fp16 P row; loads only live 32B chunks,
// writes exactly the columns gemm_pv will read (ceil((r+1)/256)*256; dead
// columns in that range get exp(masked)=0 -> zeros).
// ---------------------------------------------------------------------------
__global__ __launch_bounds__(256)
void softmax_kernel(const float* __restrict__ Sc, _Float16* __restrict__ P, int seq)
{
    const int r = blockIdx.x, b = blockIdx.y;
    const float* row = Sc + ((long)b * seq + r) * seq;
    _Float16* prow = P + ((long)b * seq + r) * seq;
    const int tid = threadIdx.x;
    const int cmax = ((r >> 8) + 1) << 8;
    const int c0 = tid * 8;

    float v[8];
    f32x4 v0, v1;
    if (c0 <= r) {
        const f32x4* rp = (const f32x4*)row;
        v0 = rp[tid * 2];
        v1 = rp[tid * 2 + 1];
    } else {
        v0 = (f32x4)(-3.0e38f);
        v1 = (f32x4)(-3.0e38f);
    }
    float lmax = -3.0e38f;
#pragma unroll
    for (int k = 0; k < 4; ++k) {
        v[k]     = (c0 + k     <= r) ? v0[k] : -3.0e38f;
        v[k + 4] = (c0 + k + 4 <= r) ? v1[k] : -3.0e38f;
    }
#pragma unroll
    for (int k = 0; k < 8; ++k) lmax = fmaxf(lmax, v[k]);

    __shared__ float red[256];
    red[tid] = lmax; __syncthreads();
    for (int s = 128; s > 0; s >>= 1) {
        if (tid < s) red[tid] = fmaxf(red[tid], red[tid + s]);
        __syncthreads();
    }
    const float m = red[0];
    __syncthreads();

    float lsum = 0.0f;
#pragma unroll
    for (int k = 0; k < 8; ++k) {
        float e = (v[k] > -1.0e38f) ? __expf(v[k] - m) : 0.0f;
        v[k] = e;
        lsum += e;
    }
    red[tid] = lsum; __syncthreads();
    for (int s = 128; s > 0; s >>= 1) {
        if (tid < s) red[tid] += red[tid + s];
        __syncthreads();
    }
    const float inv = 1.0f / red[0];

    if (c0 < cmax) {
        f16x8v o;
#pragma unroll
        for (int k = 0; k < 8; ++k) o[k] = (_Float16)(v[k] * inv);
        ((f16x8v*)prow)[tid] = o;
    }
}

// ---------------------------------------------------------------------------
extern "C" void kernel_launch(void* const* d_in, const int* in_sizes, int n_in,
                              void* d_out, int out_size, void* d_ws, size_t ws_size,
                              hipStream_t stream)
{
    constexpr int B = 4, S = 2048, D = 1024;
    constexpr long MB = 1024 * 1024;
    const float* x  = (const float*)d_in[0];
    const float* Wq = (const float*)d_in[1];
    const float* bq = (const float*)d_in[2];
    const float* Wk = (const float*)d_in[3];
    const float* bk = (const float*)d_in[4];
    const float* Wv = (const float*)d_in[5];
    const float* bv = (const float*)d_in[6];
    float* out = (float*)d_out;

    // workspace layout (160 MB; Sc overlaps dead x/W regions)
    char* ws = (char*)d_ws;
    _Float16* x_h   = (_Float16*)(ws + 0);         // 16 MB
    _Float16* W2    = (_Float16*)(ws + 16 * MB);   // 8 MB [2048][2048]
    _Float16* Wvt_h = (_Float16*)(ws + 24 * MB);   // 2 MB [1024][1024]
    float*    Sc    = (float*)(ws + 0);            // 64 MB, after x/W dead
    _Float16* Q_h   = (_Float16*)(ws + 64 * MB);   // 16 MB [M][1024]
    _Float16* Khl   = (_Float16*)(ws + 80 * MB);   // 32 MB [M][2048] hi|lo
    _Float16* Vt    = (_Float16*)(ws + 112 * MB);  // 16 MB [B][D][S]
    _Float16* P     = (_Float16*)(ws + 128 * MB);  // 32 MB [B][S][S]

    const int M = B * S;  // 8192
    dim3 blk(256);

    convert_h<<<(M * D / 4 + 255) / 256, blk, 0, stream>>>(x, x_h, (long)M * D / 4);
    transpose_w3<<<dim3(D / 32, D / 32, 3), blk, 0, stream>>>(
        Wq, Wk, Wv, W2, Wvt_h, D);

    // projections: blocks 0-255 QK, 256-383 V
    proj8<<<dim3(384), dim3(512), 0, stream>>>(
        x_h, W2, Wvt_h, Q_h, Khl, Vt, bq, bk, bv);

    // scores: causal-packed 256x256 tiles, 36/batch
    gemm_sc<<<dim3(36, B), dim3(512), 0, stream>>>(Q_h, Khl, Sc);

    // causal softmax: fp32 Sc -> fp16 P (256-aligned live region)
    softmax_kernel<<<dim3(S, B), blk, 0, stream>>>(Sc, P, S);

    // out = P @ V: 256x128 tiles, heavy rows first
    gemm_pv<<<dim3(8, 8, B), dim3(256), 0, stream>>>(P, Vt, out);
}